// Round 13
// baseline (222.794 us; speedup 1.0000x reference)
//
#include <hip/hip_runtime.h>
#include <hip/hip_bf16.h>

#define N_SAMPLES 128
#define SEG 4                  // threads per ray
#define SPT (N_SAMPLES / SEG)  // 32 samples per thread
#define LAST_DIST 1e10f
#define EPS 1e-10f

__device__ __forceinline__ float fast_sigmoid(float x) {
    return __builtin_amdgcn_rcpf(1.0f + __expf(-x));
}

// 4 threads per ray; thread q owns the contiguous samples [q*32, q*32+32).
// Serial in-register cumprod per thread (no wave-wide scan); the only
// cross-lane traffic is a 4-lane segmented combine: ~10 shuffles / 16 rays.
__global__ __launch_bounds__(256, 2) void render_rays_kernel(
    const float4* __restrict__ raw,   // [R*S] float4 (rgb + sigma)
    const float4* __restrict__ z4,    // [R*S/4] z_vals packed as float4
    float* __restrict__ out,          // [R*3]
    int n_rays)
{
    const int tid = blockIdx.x * blockDim.x + threadIdx.x;
    const int ray = tid >> 2;
    const int q   = tid & 3;
    if (ray >= n_rays) return;

    const size_t sbase = (size_t)ray * N_SAMPLES + (size_t)q * SPT;
    const float4* rp = raw + sbase;          // 32 float4, contiguous per thread
    const float4* zp = z4 + (sbase >> 2);    // 8 float4, contiguous per thread

    // ---- z values for this segment (fully unrolled -> registers) ----
    float zl[SPT];
    #pragma unroll
    for (int c = 0; c < SPT / 4; ++c) {
        const float4 zv = zp[c];
        zl[4 * c + 0] = zv.x;
        zl[4 * c + 1] = zv.y;
        zl[4 * c + 2] = zv.z;
        zl[4 * c + 3] = zv.w;
    }
    // boundary: next segment's first z (lane+1 within the quad); q==3 unused
    const float z_bound = __shfl_down(zl[0], 1);

    // ---- serial integration over 32 samples ----
    float T = 1.0f;                    // running local transmittance (exclusive)
    float cr = 0.0f, cg = 0.0f, cb = 0.0f;
    #pragma unroll
    for (int s = 0; s < SPT; ++s) {
        const float4 f = rp[s];
        float d;
        if (s < SPT - 1)      d = zl[s + 1] - zl[s];
        else if (q == SEG - 1) d = LAST_DIST;
        else                   d = z_bound - zl[SPT - 1];
        const float e = __expf(-fmaxf(f.w, 0.0f) * d);  // 1 - alpha
        const float w = (1.0f - e) * T;                  // alpha * trans_local
        cr = fmaf(w, fast_sigmoid(f.x), cr);
        cg = fmaf(w, fast_sigmoid(f.y), cg);
        cb = fmaf(w, fast_sigmoid(f.z), cb);
        T *= (e + EPS);                                  // t = 1 - alpha + eps
    }
    // T = product of this segment's t values

    // ---- quad-segmented exclusive product scan (3 shuffles) ----
    float Pinc = T;
    float u = __shfl_up(Pinc, 1); if (q >= 1) Pinc *= u;
    u       = __shfl_up(Pinc, 2); if (q >= 2) Pinc *= u;
    float Tstart = __shfl_up(Pinc, 1);
    if (q == 0) Tstart = 1.0f;

    // scale local color by segment-start transmittance, reduce over quad
    cr *= Tstart; cg *= Tstart; cb *= Tstart;
    cr += __shfl_xor(cr, 1); cg += __shfl_xor(cg, 1); cb += __shfl_xor(cb, 1);
    cr += __shfl_xor(cr, 2); cg += __shfl_xor(cg, 2); cb += __shfl_xor(cb, 2);

    if (q == 0) {
        const size_t o = (size_t)ray * 3;
        out[o + 0] = cr;
        out[o + 1] = cg;
        out[o + 2] = cb;
    }
}

extern "C" void kernel_launch(void* const* d_in, const int* in_sizes, int n_in,
                              void* d_out, int out_size, void* d_ws, size_t ws_size,
                              hipStream_t stream) {
    const float4* raw = (const float4*)d_in[0];   // [R, S, 4] f32
    const float4* z4  = (const float4*)d_in[1];   // [R, S]   f32 (as float4)
    float* out        = (float*)d_out;            // [R, 3]   f32

    const int n_rays = in_sizes[0] / (N_SAMPLES * 4);

    const int block = 256;
    const long long total_threads = (long long)n_rays * SEG;
    const int grid = (int)((total_threads + block - 1) / block);

    render_rays_kernel<<<grid, block, 0, stream>>>(raw, z4, out, n_rays);
}

// Round 15
// 204.538 us; speedup vs baseline: 1.0893x; 1.0893x over previous
//
#include <hip/hip_runtime.h>
#include <hip/hip_bf16.h>

#define N_SAMPLES 128
#define LAST_DIST 1e10f
#define EPS 1e-10f

// DPP ctrl encodings (gfx9/CDNA lineage, valid on gfx950)
#define DPP_ROW_SHR(n)   (0x110 | (n))   // lane i <- lane i-n (within 16-lane row)
#define DPP_WAVE_SHL1    0x130           // lane i <- lane i+1 (whole wave)
#define DPP_WAVE_SHR1    0x138           // lane i <- lane i-1 (whole wave)
#define DPP_ROW_BCAST15  0x142           // lane15 -> lanes16..31, lane47 -> 48..63
#define DPP_ROW_BCAST31  0x143           // lane31 -> lanes32..63

// update_dpp: disabled/invalid lanes receive `oldv` (bound_ctrl=false)
template <int Ctrl, int RowMask = 0xf, int BankMask = 0xf>
__device__ __forceinline__ float dpp_mov(float oldv, float src) {
    return __int_as_float(__builtin_amdgcn_update_dpp(
        __float_as_int(oldv), __float_as_int(src), Ctrl, RowMask, BankMask, false));
}

__device__ __forceinline__ float readlane_f(float v, int lane) {
    return __int_as_float(__builtin_amdgcn_readlane(__float_as_int(v), lane));
}

// 64-lane inclusive prefix product, pure DPP (identity = 1.0)
__device__ __forceinline__ float wave_iprod(float t) {
    float p = t;
    p *= dpp_mov<DPP_ROW_SHR(1)>(1.0f, p);
    p *= dpp_mov<DPP_ROW_SHR(2)>(1.0f, p);
    p *= dpp_mov<DPP_ROW_SHR(4)>(1.0f, p);
    p *= dpp_mov<DPP_ROW_SHR(8)>(1.0f, p);
    p *= dpp_mov<DPP_ROW_BCAST15, 0xa>(1.0f, p);   // rows 1,3 only
    p *= dpp_mov<DPP_ROW_BCAST31, 0xc>(1.0f, p);   // rows 2,3 only
    return p;
}

// 64-lane sum; result valid in lane 63 (inclusive sum-scan, identity = 0)
__device__ __forceinline__ float wave_sum63(float v) {
    v += dpp_mov<DPP_ROW_SHR(1)>(0.0f, v);
    v += dpp_mov<DPP_ROW_SHR(2)>(0.0f, v);
    v += dpp_mov<DPP_ROW_SHR(4)>(0.0f, v);
    v += dpp_mov<DPP_ROW_SHR(8)>(0.0f, v);
    v += dpp_mov<DPP_ROW_BCAST15, 0xa>(0.0f, v);
    v += dpp_mov<DPP_ROW_BCAST31, 0xc>(0.0f, v);
    return v;
}

__device__ __forceinline__ float fast_sigmoid(float x) {
    return __builtin_amdgcn_rcpf(1.0f + __expf(-x));
}

// One wave per ray, lane l owns samples (l, 64+l): every global load is
// unit-stride dense (16 lines/instr), and ALL cross-lane ops are DPP
// (full-rate VALU) -> zero LDS-pipe traffic.
__global__ __launch_bounds__(256, 8) void render_rays_kernel(
    const float4* __restrict__ raw,   // [R*S] float4 (rgb + sigma)
    const float*  __restrict__ zv,    // [R*S] z_vals
    float* __restrict__ out,          // [R*3]
    int n_rays)
{
    const int wave = threadIdx.x >> 6;
    const int lane = threadIdx.x & 63;
    const int r = blockIdx.x * (blockDim.x >> 6) + wave;
    if (r >= n_rays) return;

    const size_t base = (size_t)r * N_SAMPLES;

    // ---- dense loads ----
    const float4 fa = raw[base + lane];        // sample l
    const float4 fb = raw[base + 64 + lane];   // sample 64+l
    const float  za = zv[base + lane];
    const float  zb = zv[base + 64 + lane];

    // ---- dists via wave_shl1 (lane i <- lane i+1) ----
    const float za_next = dpp_mov<DPP_WAVE_SHL1>(0.0f, za);   // z[l+1], lane63 invalid
    const float zb_next = dpp_mov<DPP_WAVE_SHL1>(0.0f, zb);   // z[65+l], lane63 invalid
    const float z64     = readlane_f(zb, 0);                  // z[64]
    const float da = ((lane == 63) ? z64 : za_next) - za;
    const float db = (lane == 63) ? LAST_DIST : (zb_next - zb);

    // ---- survival t = 1 - alpha + eps = exp(-relu(sigma)*d) + eps ----
    const float ea = __expf(-fmaxf(fa.w, 0.0f) * da);
    const float eb = __expf(-fmaxf(fb.w, 0.0f) * db);
    const float ta = ea + EPS;
    const float tb = eb + EPS;

    // ---- transmittance: two half-scans, pure DPP ----
    const float Pa = wave_iprod(ta);
    float Ta = dpp_mov<DPP_WAVE_SHR1>(1.0f, Pa);   // exclusive; lane0 -> 1.0
    const float totA = readlane_f(Pa, 63);         // prod of all first-half t

    const float Pb = wave_iprod(tb);
    float Tb = dpp_mov<DPP_WAVE_SHR1>(1.0f, Pb) * totA;  // lane0: 1.0*totA

    // ---- weights & weighted color ----
    const float wa = (1.0f - ea) * Ta;
    const float wb = (1.0f - eb) * Tb;

    float accx = wa * fast_sigmoid(fa.x) + wb * fast_sigmoid(fb.x);
    float accy = wa * fast_sigmoid(fa.y) + wb * fast_sigmoid(fb.y);
    float accz = wa * fast_sigmoid(fa.z) + wb * fast_sigmoid(fb.z);

    // ---- DPP reduction; totals land in lane 63, which stores ----
    accx = wave_sum63(accx);
    accy = wave_sum63(accy);
    accz = wave_sum63(accz);

    if (lane == 63) {
        const size_t o = (size_t)r * 3;
        out[o + 0] = accx;
        out[o + 1] = accy;
        out[o + 2] = accz;
    }
}

extern "C" void kernel_launch(void* const* d_in, const int* in_sizes, int n_in,
                              void* d_out, int out_size, void* d_ws, size_t ws_size,
                              hipStream_t stream) {
    const float4* raw = (const float4*)d_in[0];   // [R, S, 4] f32
    const float*  zv  = (const float*)d_in[1];    // [R, S]   f32
    float* out        = (float*)d_out;            // [R, 3]   f32

    const int n_rays = in_sizes[0] / (N_SAMPLES * 4);

    const int waves_per_block = 4;                // 256 threads
    const int block = waves_per_block * 64;
    const int grid = (n_rays + waves_per_block - 1) / waves_per_block;

    render_rays_kernel<<<grid, block, 0, stream>>>(raw, zv, out, n_rays);
}